// Round 1
// baseline (178.670 us; speedup 1.0000x reference)
//
#include <hip/hip_runtime.h>

// Problem constants (reference: N=2048, F=128, HEADS=8, OUT_DIM=8, ALPHA=0.2)
#define NN      2048
#define FDIM    128
#define HEADS   8
#define ODIM    8
#define HID     64      // HEADS*ODIM
#define ALPHA   0.2f

__device__ __forceinline__ float lrelu(float x) {
    return x > 0.f ? x : ALPHA * x;
}

// ---------------------------------------------------------------------------
// Kernel 1: h = X @ W  (per-node row), s1 = h . a1, s2 = h . a2  (per head)
// grid = NN blocks, block = 64 threads (1 wave)
// ---------------------------------------------------------------------------
__global__ __launch_bounds__(64) void gat_prep(
        const float* __restrict__ X,   // (NN, FDIM)
        const float* __restrict__ W,   // (FDIM, HID)
        const float* __restrict__ ak,  // (2*ODIM,)
        float* __restrict__ H,         // (NN, HID)
        float* __restrict__ S1,        // (NN, HEADS)
        float* __restrict__ S2) {      // (NN, HEADS)
    const int n = blockIdx.x;
    const int t = threadIdx.x;

    __shared__ float Xs[FDIM];
    __shared__ float hs[HID];

    Xs[t]      = X[(size_t)n * FDIM + t];
    Xs[t + 64] = X[(size_t)n * FDIM + 64 + t];
    __syncthreads();

    float acc = 0.f;
    #pragma unroll 8
    for (int k = 0; k < FDIM; ++k)
        acc = fmaf(Xs[k], W[k * HID + t], acc);   // Xs[k]: LDS broadcast; W col: coalesced

    H[(size_t)n * HID + t] = acc;
    hs[t] = acc;
    __syncthreads();

    if (t < 16) {
        const int head = t & 7;
        const float* a = ak + ((t < 8) ? 0 : ODIM);
        float s = 0.f;
        #pragma unroll
        for (int d = 0; d < ODIM; ++d)
            s = fmaf(hs[head * ODIM + d], a[d], s);
        if (t < 8) S1[n * HEADS + head] = s;
        else       S2[n * HEADS + head] = s;
    }
}

// ---------------------------------------------------------------------------
// Kernel 2 (FUSED rowsum + write): per row i —
//   pass A: LF[h] = sum_j mask(i,j) * exp(lrelu(s1[i,h]+s2[j,h]))  (block reduce)
//   pass B: out[i,j,d] = lrelu( sum_h p[j,h] * h[i,h,d] / LF[h] )
// A row staged in LDS ONCE (was read twice across two kernels before);
// no LF global round-trip; one launch instead of two.
// Max-free softmax: scores are O(1); masked lanes contribute exactly 0,
// matching reference's exp(-1e9) == 0 in fp32.
// grid = NN blocks, block = 256 (4 waves), 8 j per thread
// ---------------------------------------------------------------------------
__global__ __launch_bounds__(256, 4) void gat_fused(
        const int*   __restrict__ A,    // (NN, NN)
        const float* __restrict__ H,    // (NN, HID)
        const float* __restrict__ S1,   // (NN, HEADS)
        const float* __restrict__ S2,   // (NN, HEADS)
        float* __restrict__ out) {      // (NN, NN, ODIM)
    const int i    = blockIdx.x;
    const int t    = threadIdx.x;
    const int wave = t >> 6;
    const int lane = t & 63;

    __shared__ int   As[NN];            // 8 KB adjacency row
    __shared__ float hhS[HID];          // raw H row (divide happens later)
    __shared__ float redL[4 * HEADS];   // per-wave partial denominators
    __shared__ float LFs[HEADS];        // final denominators

    const int4* Arow4 = (const int4*)(A + (size_t)i * NN);
    ((int4*)As)[t]       = Arow4[t];
    ((int4*)As)[t + 256] = Arow4[t + 256];

    if (t < HID)
        hhS[t] = H[(size_t)i * HID + t];

    float s1r[HEADS];
    #pragma unroll
    for (int h = 0; h < HEADS; ++h) s1r[h] = S1[i * HEADS + h];

    __syncthreads();

    // ---- pass A: softmax denominators ---------------------------------
    float ls[HEADS];
    #pragma unroll
    for (int h = 0; h < HEADS; ++h) ls[h] = 0.f;

    #pragma unroll
    for (int jj = 0; jj < 8; ++jj) {
        const int j = t + jj * 256;
        const float4 s2a = *(const float4*)(S2 + j * HEADS);
        const float4 s2b = *(const float4*)(S2 + j * HEADS + 4);
        const bool msk = As[j] > 0;
        const float s2v[8] = {s2a.x, s2a.y, s2a.z, s2a.w,
                              s2b.x, s2b.y, s2b.z, s2b.w};
        #pragma unroll
        for (int h = 0; h < HEADS; ++h) {
            const float x = s1r[h] + s2v[h];
            ls[h] += msk ? __expf(lrelu(x)) : 0.f;
        }
    }

    #pragma unroll
    for (int h = 0; h < HEADS; ++h) {
        float v = ls[h];
        #pragma unroll
        for (int off = 32; off; off >>= 1)
            v += __shfl_xor(v, off);
        if (lane == 0) redL[wave * HEADS + h] = v;
    }
    __syncthreads();

    if (t < HEADS) {
        float v = 0.f;
        #pragma unroll
        for (int w = 0; w < 4; ++w)
            v += redL[w * HEADS + t];
        LFs[t] = v;
    }
    __syncthreads();

    // ---- pass B: recompute p, scale by hh/LF, stream output ------------
    // hh pre-divided into registers; hot loop is reg-only (LDS: As reads).
    float hh[HID];
    #pragma unroll
    for (int h = 0; h < HEADS; ++h) {
        const float inv = 1.0f / LFs[h];
        #pragma unroll
        for (int d = 0; d < ODIM; ++d)
            hh[h * ODIM + d] = hhS[h * ODIM + d] * inv;
    }

    #pragma unroll
    for (int jj = 0; jj < 8; ++jj) {
        const int j = t + jj * 256;
        const float4 s2a = *(const float4*)(S2 + j * HEADS);
        const float4 s2b = *(const float4*)(S2 + j * HEADS + 4);
        const bool msk = As[j] > 0;
        const float s2v[8] = {s2a.x, s2a.y, s2a.z, s2a.w,
                              s2b.x, s2b.y, s2b.z, s2b.w};

        float p[HEADS];
        #pragma unroll
        for (int h = 0; h < HEADS; ++h) {
            const float x = s1r[h] + s2v[h];
            p[h] = msk ? __expf(lrelu(x)) : 0.f;
        }

        float o[ODIM];
        #pragma unroll
        for (int d = 0; d < ODIM; ++d) o[d] = 0.f;
        #pragma unroll
        for (int h = 0; h < HEADS; ++h) {
            #pragma unroll
            for (int d = 0; d < ODIM; ++d)
                o[d] = fmaf(p[h], hh[h * ODIM + d], o[d]);
        }

        const size_t base = ((size_t)i * NN + j) * ODIM;
        float4 o0, o1;
        o0.x = lrelu(o[0]); o0.y = lrelu(o[1]);
        o0.z = lrelu(o[2]); o0.w = lrelu(o[3]);
        o1.x = lrelu(o[4]); o1.y = lrelu(o[5]);
        o1.z = lrelu(o[6]); o1.w = lrelu(o[7]);
        *(float4*)(out + base)     = o0;   // coalesced 32 B/lane contiguous
        *(float4*)(out + base + 4) = o1;
    }
}

// ---------------------------------------------------------------------------
extern "C" void kernel_launch(void* const* d_in, const int* in_sizes, int n_in,
                              void* d_out, int out_size, void* d_ws, size_t ws_size,
                              hipStream_t stream) {
    const float* X  = (const float*)d_in[0];   // (2048,128) fp32
    const int*   A  = (const int*)  d_in[1];   // (2048,2048) int32
    const float* W  = (const float*)d_in[2];   // (128,64) fp32
    const float* ak = (const float*)d_in[3];   // (16,1) fp32
    float* out = (float*)d_out;                // (2048*2048*8) fp32

    // workspace layout: H (512 KB) | S1 (64 KB) | S2 (64 KB)
    float* H  = (float*)d_ws;
    float* S1 = H  + (size_t)NN * HID;
    float* S2 = S1 + (size_t)NN * HEADS;

    gat_prep <<<NN,  64, 0, stream>>>(X, W, ak, H, S1, S2);
    gat_fused<<<NN, 256, 0, stream>>>(A, H, S1, S2, out);
}

// Round 2
// 175.495 us; speedup vs baseline: 1.0181x; 1.0181x over previous
//
#include <hip/hip_runtime.h>

// Problem constants (reference: N=2048, F=128, HEADS=8, OUT_DIM=8, ALPHA=0.2)
#define NN      2048
#define FDIM    128
#define HEADS   8
#define ODIM    8
#define HID     64      // HEADS*ODIM
#define ALPHA   0.2f

__device__ __forceinline__ float lrelu(float x) {
    return x > 0.f ? x : ALPHA * x;
}

// ---------------------------------------------------------------------------
// Kernel 1: h = X @ W  (per-node row), s1 = h . a1, s2 = h . a2  (per head)
// grid = NN blocks, block = 64 threads (1 wave)
// ---------------------------------------------------------------------------
__global__ __launch_bounds__(64) void gat_prep(
        const float* __restrict__ X,   // (NN, FDIM)
        const float* __restrict__ W,   // (FDIM, HID)
        const float* __restrict__ ak,  // (2*ODIM,)
        float* __restrict__ H,         // (NN, HID)
        float* __restrict__ S1,        // (NN, HEADS)
        float* __restrict__ S2) {      // (NN, HEADS)
    const int n = blockIdx.x;
    const int t = threadIdx.x;

    __shared__ float Xs[FDIM];
    __shared__ float hs[HID];

    Xs[t]      = X[(size_t)n * FDIM + t];
    Xs[t + 64] = X[(size_t)n * FDIM + 64 + t];
    __syncthreads();

    float acc = 0.f;
    #pragma unroll 8
    for (int k = 0; k < FDIM; ++k)
        acc = fmaf(Xs[k], W[k * HID + t], acc);   // Xs[k]: LDS broadcast; W col: coalesced

    H[(size_t)n * HID + t] = acc;
    hs[t] = acc;
    __syncthreads();

    if (t < 16) {
        const int head = t & 7;
        const float* a = ak + ((t < 8) ? 0 : ODIM);
        float s = 0.f;
        #pragma unroll
        for (int d = 0; d < ODIM; ++d)
            s = fmaf(hs[head * ODIM + d], a[d], s);
        if (t < 8) S1[n * HEADS + head] = s;
        else       S2[n * HEADS + head] = s;
    }
}

// ---------------------------------------------------------------------------
// Kernel 2 (FUSED rowsum + write): per row i —
//   pass A: LF[h] = sum_j mask(i,j) * exp(lrelu(s1[i,h]+s2[j,h]))  (block reduce)
//   pass B: out[i,j,d] = lrelu( sum_h p[j,h] * h[i,h,d] / LF[h] )
//
// R1 change: __launch_bounds__(256, 2) instead of (256, 4).
//   (256,4) capped the allocator at 128 VGPR; the compiler demoted hh[64]
//   to SCRATCH (VGPR_Count=64 with ~130 live floats — impossible without
//   spill). Pass B's 512 FMA/thread then each read hh from scratch →
//   latency-bound at 1.08 TB/s, VALUBusy 3%. Cap 256 VGPR + unroll-2 on
//   the j loop keeps peak pressure ~110-128 → hh stays in registers.
// grid = NN blocks, block = 256 (4 waves), 8 j per thread
// ---------------------------------------------------------------------------
__global__ __launch_bounds__(256, 2) void gat_fused(
        const int*   __restrict__ A,    // (NN, NN)
        const float* __restrict__ H,    // (NN, HID)
        const float* __restrict__ S1,   // (NN, HEADS)
        const float* __restrict__ S2,   // (NN, HEADS)
        float* __restrict__ out) {      // (NN, NN, ODIM)
    const int i    = blockIdx.x;
    const int t    = threadIdx.x;
    const int wave = t >> 6;
    const int lane = t & 63;

    __shared__ int   As[NN];            // 8 KB adjacency row
    __shared__ float hhS[HID];          // raw H row (divide happens later)
    __shared__ float redL[4 * HEADS];   // per-wave partial denominators
    __shared__ float LFs[HEADS];        // final denominators

    const int4* Arow4 = (const int4*)(A + (size_t)i * NN);
    ((int4*)As)[t]       = Arow4[t];
    ((int4*)As)[t + 256] = Arow4[t + 256];

    if (t < HID)
        hhS[t] = H[(size_t)i * HID + t];

    float s1r[HEADS];
    #pragma unroll
    for (int h = 0; h < HEADS; ++h) s1r[h] = S1[i * HEADS + h];

    __syncthreads();

    // ---- pass A: softmax denominators ---------------------------------
    float ls[HEADS];
    #pragma unroll
    for (int h = 0; h < HEADS; ++h) ls[h] = 0.f;

    #pragma unroll 2
    for (int jj = 0; jj < 8; ++jj) {
        const int j = t + jj * 256;
        const float4 s2a = *(const float4*)(S2 + j * HEADS);
        const float4 s2b = *(const float4*)(S2 + j * HEADS + 4);
        const bool msk = As[j] > 0;
        const float s2v[8] = {s2a.x, s2a.y, s2a.z, s2a.w,
                              s2b.x, s2b.y, s2b.z, s2b.w};
        #pragma unroll
        for (int h = 0; h < HEADS; ++h) {
            const float x = s1r[h] + s2v[h];
            ls[h] += msk ? __expf(lrelu(x)) : 0.f;
        }
    }

    #pragma unroll
    for (int h = 0; h < HEADS; ++h) {
        float v = ls[h];
        #pragma unroll
        for (int off = 32; off; off >>= 1)
            v += __shfl_xor(v, off);
        if (lane == 0) redL[wave * HEADS + h] = v;
    }
    __syncthreads();

    if (t < HEADS) {
        float v = 0.f;
        #pragma unroll
        for (int w = 0; w < 4; ++w)
            v += redL[w * HEADS + t];
        LFs[t] = v;
    }
    __syncthreads();

    // ---- pass B: recompute p, scale by hh/LF, stream output ------------
    // hh pre-divided into REGISTERS (all indices compile-time constant);
    // hot loop is reg-only except the As broadcast read + s2 L2-hit loads.
    float hh[HID];
    #pragma unroll
    for (int h = 0; h < HEADS; ++h) {
        const float inv = 1.0f / LFs[h];
        const float4 va = *(const float4*)(hhS + h * ODIM);
        const float4 vb = *(const float4*)(hhS + h * ODIM + 4);
        hh[h * ODIM + 0] = va.x * inv;
        hh[h * ODIM + 1] = va.y * inv;
        hh[h * ODIM + 2] = va.z * inv;
        hh[h * ODIM + 3] = va.w * inv;
        hh[h * ODIM + 4] = vb.x * inv;
        hh[h * ODIM + 5] = vb.y * inv;
        hh[h * ODIM + 6] = vb.z * inv;
        hh[h * ODIM + 7] = vb.w * inv;
    }

    #pragma unroll 2
    for (int jj = 0; jj < 8; ++jj) {
        const int j = t + jj * 256;
        const float4 s2a = *(const float4*)(S2 + j * HEADS);
        const float4 s2b = *(const float4*)(S2 + j * HEADS + 4);
        const bool msk = As[j] > 0;
        const float s2v[8] = {s2a.x, s2a.y, s2a.z, s2a.w,
                              s2b.x, s2b.y, s2b.z, s2b.w};

        float p[HEADS];
        #pragma unroll
        for (int h = 0; h < HEADS; ++h) {
            const float x = s1r[h] + s2v[h];
            p[h] = msk ? __expf(lrelu(x)) : 0.f;
        }

        float o[ODIM];
        #pragma unroll
        for (int d = 0; d < ODIM; ++d) o[d] = 0.f;
        #pragma unroll
        for (int h = 0; h < HEADS; ++h) {
            #pragma unroll
            for (int d = 0; d < ODIM; ++d)
                o[d] = fmaf(p[h], hh[h * ODIM + d], o[d]);
        }

        const size_t base = ((size_t)i * NN + j) * ODIM;
        float4 o0, o1;
        o0.x = lrelu(o[0]); o0.y = lrelu(o[1]);
        o0.z = lrelu(o[2]); o0.w = lrelu(o[3]);
        o1.x = lrelu(o[4]); o1.y = lrelu(o[5]);
        o1.z = lrelu(o[6]); o1.w = lrelu(o[7]);
        *(float4*)(out + base)     = o0;   // coalesced 32 B/lane contiguous
        *(float4*)(out + base + 4) = o1;
    }
}

// ---------------------------------------------------------------------------
extern "C" void kernel_launch(void* const* d_in, const int* in_sizes, int n_in,
                              void* d_out, int out_size, void* d_ws, size_t ws_size,
                              hipStream_t stream) {
    const float* X  = (const float*)d_in[0];   // (2048,128) fp32
    const int*   A  = (const int*)  d_in[1];   // (2048,2048) int32
    const float* W  = (const float*)d_in[2];   // (128,64) fp32
    const float* ak = (const float*)d_in[3];   // (16,1) fp32
    float* out = (float*)d_out;                // (2048*2048*8) fp32

    // workspace layout: H (512 KB) | S1 (64 KB) | S2 (64 KB)
    float* H  = (float*)d_ws;
    float* S1 = H  + (size_t)NN * HID;
    float* S2 = S1 + (size_t)NN * HEADS;

    gat_prep <<<NN,  64, 0, stream>>>(X, W, ak, H, S1, S2);
    gat_fused<<<NN, 256, 0, stream>>>(A, H, S1, S2, out);
}